// Round 4
// baseline (732.221 us; speedup 1.0000x reference)
//
#include <hip/hip_runtime.h>

// ============================================================================
// VectorChannel, round 4: MFMA gemm (split-precision bf16) + fp32 P + lean node_k.
//   logits[e] = PA[col] + PB[row]; P = [hb_hi + hb_lo] @ Wtb (bf16 MFMA, fp32 out)
//   k-packing inside MFMA operands is a shared bijection => layout-safe.
//   node_k: fused 2-moment LN, sv[96] float4 LDS reads, weights in-place.
// ============================================================================

#define DD 128
#define VV 16
#define TV 48      // 3*V
#define NK 512     // 2*V*V

typedef __attribute__((ext_vector_type(8))) short short8;   // 8 bf16 (4 VGPR)
typedef __attribute__((ext_vector_type(4))) float f32x4;

__device__ __forceinline__ unsigned short f2bf(float f){
    union{float f; unsigned u;} v; v.f = f;
    unsigned r = v.u + 0x7fffu + ((v.u >> 16) & 1u);   // RTNE
    return (unsigned short)(r >> 16);
}
__device__ __forceinline__ float bf2f(unsigned short h){
    union{unsigned u; float f;} v; v.u = ((unsigned)h) << 16; return v.f;
}

// --- detect whether edge_index is int64 (all high dwords zero) ---------------
__global__ void detect_i64(const int* p, int nchk, int* flag){
    __shared__ int s;
    if (threadIdx.x == 0) s = 0;
    __syncthreads();
    int nz = 0;
    for (int i = threadIdx.x; i < nchk; i += blockDim.x) nz |= (p[2*i+1] != 0);
    if (nz) atomicOr(&s, 1);
    __syncthreads();
    if (threadIdx.x == 0) *flag = s ? 0 : 1;   // 1 => int64
}

__global__ void zero_cnt(int* cnt, int n){
    int i = blockIdx.x*blockDim.x + threadIdx.x;
    if (i < n) cnt[i] = 0;
}

// convert indices to i32 AND histogram the cols
__global__ void cvt_hist(const void* __restrict__ src, int* __restrict__ dst,
                         int* __restrict__ cnt, int n, int E,
                         const int* __restrict__ flag){
    int i = blockIdx.x*blockDim.x + threadIdx.x;
    if (i >= n) return;
    int v = (*flag) ? (int)((const long long*)src)[i] : ((const int*)src)[i];
    dst[i] = v;
    if (i >= E) atomicAdd(&cnt[v], 1);   // i>=E => col array
}

// exclusive scan of cnt[N] -> start[N+1], cursor copy (1 block)
__global__ __launch_bounds__(1024) void scan_k(const int* __restrict__ cnt,
        int* __restrict__ start, int* __restrict__ cursor, int N){
    __shared__ int wsum[16];
    __shared__ int woff[16];
    __shared__ int btot;
    __shared__ int carry;
    int tid = threadIdx.x;
    int lane = tid & 63, wid = tid >> 6;
    if (tid == 0) carry = 0;
    __syncthreads();
    for (int base = 0; base < N; base += 1024){
        int i = base + tid;
        int x = (i < N) ? cnt[i] : 0;
        int v = x;
        #pragma unroll
        for (int off = 1; off < 64; off <<= 1){
            int t = __shfl_up(v, off, 64);
            if (lane >= off) v += t;
        }
        if (lane == 63) wsum[wid] = v;
        __syncthreads();
        if (wid == 0 && lane < 16){
            int s = wsum[lane];
            int sv = s;
            #pragma unroll
            for (int off = 1; off < 16; off <<= 1){
                int t = __shfl_up(sv, off, 64);
                if (lane >= off) sv += t;
            }
            woff[lane] = sv - s;
            if (lane == 15) btot = sv;
        }
        __syncthreads();
        if (i < N){
            int excl = v - x + woff[wid] + carry;
            start[i] = excl;
            cursor[i] = excl;
        }
        __syncthreads();
        if (tid == 0) carry += btot;
        __syncthreads();
    }
    if (tid == 0) start[N] = carry;
}

__global__ void scatter_k(const int* __restrict__ idx, int* __restrict__ cursor,
                          int* __restrict__ elist, int E){
    int e = blockIdx.x*blockDim.x + threadIdx.x;
    if (e >= E) return;
    int col = idx[E + e], row = idx[e];
    int pos = atomicAdd(&cursor[col], 1);
    elist[pos] = row;
}

// --- build permuted bf16 weight matrix [1024 cols][128 k] + params -----------
// col j<512: PA (c=j/32,kk=j%32 -> k=kk*16+c, Wi[k][0:128], bias bi[k])
//     j>=512: PB (Wi[k][128:256], bias 0). gi_t/bbi_t pre-negated for sigmoid.
__global__ void build_wt(const float* __restrict__ Wi, const float* __restrict__ bi,
                         const float* __restrict__ gi, const float* __restrict__ bbi,
                         unsigned short* __restrict__ Wtb, float* __restrict__ bias_t,
                         float* __restrict__ gi_t, float* __restrict__ bbi_t){
    int j = blockIdx.x;        // 0..1023
    int d = threadIdx.x;       // 0..127
    int half = j >> 9;
    int jj = j & 511;
    int c = jj >> 5, kk = jj & 31;
    int k = kk*16 + c;
    Wtb[(size_t)j*128 + d] = f2bf(Wi[k*256 + half*128 + d]);
    if (d == 0){
        bias_t[j] = half ? 0.0f : bi[k];
        if (!half){ gi_t[jj] = -gi[k]; bbi_t[jj] = -bbi[k]; }   // negated
    }
}

// --- split h into hi/lo bf16 (pad rows -> 0) ---------------------------------
__global__ void cast_h(const float* __restrict__ h, unsigned short* __restrict__ hbh,
                       unsigned short* __restrict__ hbl, int N, int total){
    int i = blockIdx.x*blockDim.x + threadIdx.x;
    if (i >= total) return;
    int m = i >> 7;
    float v = (m < N) ? h[i] : 0.0f;
    unsigned short hi = f2bf(v);
    float lo = v - bf2f(hi);
    hbh[i] = hi;
    hbl[i] = f2bf(lo);
}

// --- vector_init: 2x (Linear+LN+SiLU), one wave per node; also emit g=R@v ----
__device__ __forceinline__ float waveRedSum64(float v){
    #pragma unroll
    for (int off = 32; off > 0; off >>= 1) v += __shfl_xor(v, off, 64);
    return v;
}
__global__ __launch_bounds__(256) void vinit(
        const float* __restrict__ h,
        const float* __restrict__ W1, const float* __restrict__ b1,
        const float* __restrict__ g1, const float* __restrict__ bb1,
        const float* __restrict__ W2, const float* __restrict__ b2,
        const float* __restrict__ g2, const float* __restrict__ bb2,
        const float* __restrict__ frames,
        float* __restrict__ vecs, float* __restrict__ gvec, int N){
    __shared__ float hs[4][DD];
    __shared__ float ts[4][TV];
    int w = threadIdx.x >> 6, l = threadIdx.x & 63;
    int n = blockIdx.x*4 + w;
    int nr = n < N ? n : N-1;
    hs[w][l]      = h[(size_t)nr*DD + l];
    hs[w][l + 64] = h[(size_t)nr*DD + 64 + l];
    __syncthreads();

    float o1 = 0.0f;
    if (l < TV){
        o1 = b1[l];
        const float* wr = W1 + l*DD;
        #pragma unroll
        for (int d = 0; d < DD; d += 4){
            float4 w4 = *(const float4*)(wr + d);
            o1 += hs[w][d]*w4.x + hs[w][d+1]*w4.y + hs[w][d+2]*w4.z + hs[w][d+3]*w4.w;
        }
    }
    float s  = waveRedSum64(l < TV ? o1 : 0.0f);
    float mu = s * (1.0f/TV);
    float dv = l < TV ? (o1 - mu) : 0.0f;
    float sq = waveRedSum64(dv*dv);
    float inv = rsqrtf(sq*(1.0f/TV) + 1e-5f);
    if (l < TV){
        float y = g1[l]*(dv*inv) + bb1[l];
        ts[w][l] = y / (1.0f + __expf(-y));
    }
    __syncthreads();

    float o2 = 0.0f;
    if (l < TV){
        o2 = b2[l];
        const float* wr = W2 + l*TV;
        #pragma unroll
        for (int j = 0; j < TV; j += 4){
            float4 w4 = *(const float4*)(wr + j);
            o2 += ts[w][j]*w4.x + ts[w][j+1]*w4.y + ts[w][j+2]*w4.z + ts[w][j+3]*w4.w;
        }
    }
    s  = waveRedSum64(l < TV ? o2 : 0.0f);
    mu = s * (1.0f/TV);
    dv = l < TV ? (o2 - mu) : 0.0f;
    sq = waveRedSum64(dv*dv);
    inv = rsqrtf(sq*(1.0f/TV) + 1e-5f);
    __syncthreads();
    if (l < TV){
        float y = g2[l]*(dv*inv) + bb2[l];
        float t2 = y / (1.0f + __expf(-y));
        if (n < N) vecs[(size_t)n*TV + l] = t2;
        ts[w][l] = t2;
    }
    __syncthreads();
    if (l < TV && n < N){
        int cc = l/3, oo = l%3;  // g[n][cc][oo] = sum_j R[oo][j]*v[cc][j]
        const float* R = frames + (size_t)n*9;
        float gv = R[oo*3+0]*ts[w][cc*3+0] + R[oo*3+1]*ts[w][cc*3+1] + R[oo*3+2]*ts[w][cc*3+2];
        gvec[(size_t)n*TV + l] = gv;
    }
}

// --- P = (h_hi + h_lo) @ Wtb^T + bias : MFMA bf16, fp32 out ------------------
// Wave computes 16 rows x 256 cols. A/B k-packing: elems 0-3 <- k=kb..kb+3,
// elems 4-7 <- k=kb+16..kb+19, kb = ks + 4*(lane>>4). Same bijection both
// operands => correct regardless of HW k-slot order. C/D: col=lane&15,
// row=(lane>>4)*4+reg  [m89-verified].
__global__ __launch_bounds__(256) void gemm_mfma(
        const unsigned short* __restrict__ hbh, const unsigned short* __restrict__ hbl,
        const unsigned short* __restrict__ Wtb, const float* __restrict__ bias_t,
        float* __restrict__ P, int Np){
    int wv = threadIdx.x >> 6, l = threadIdx.x & 63;
    int lr = l & 15, g = l >> 4;
    int m0 = (blockIdx.y*4 + wv)*16;
    int n0 = blockIdx.x*256;

    f32x4 acc[16];
    #pragma unroll
    for (int nf = 0; nf < 16; nf++) acc[nf] = (f32x4){0.f,0.f,0.f,0.f};

    const unsigned short* arow_h = hbh + (size_t)(m0 + lr)*128;
    const unsigned short* arow_l = hbl + (size_t)(m0 + lr)*128;

    #pragma unroll
    for (int ks = 0; ks < 128; ks += 32){
        int kb = ks + 4*g;
        short8 ah, al;
        ((ushort4*)&ah)[0] = *(const ushort4*)(arow_h + kb);
        ((ushort4*)&ah)[1] = *(const ushort4*)(arow_h + kb + 16);
        ((ushort4*)&al)[0] = *(const ushort4*)(arow_l + kb);
        ((ushort4*)&al)[1] = *(const ushort4*)(arow_l + kb + 16);
        #pragma unroll
        for (int nf = 0; nf < 16; nf++){
            const unsigned short* brow = Wtb + (size_t)(n0 + nf*16 + lr)*128;
            short8 b;
            ((ushort4*)&b)[0] = *(const ushort4*)(brow + kb);
            ((ushort4*)&b)[1] = *(const ushort4*)(brow + kb + 16);
            acc[nf] = __builtin_amdgcn_mfma_f32_16x16x32_bf16(ah, b, acc[nf], 0, 0, 0);
            acc[nf] = __builtin_amdgcn_mfma_f32_16x16x32_bf16(al, b, acc[nf], 0, 0, 0);
        }
    }
    #pragma unroll
    for (int nf = 0; nf < 16; nf++){
        int col = n0 + nf*16 + lr;
        float bs = bias_t[col];
        #pragma unroll
        for (int r = 0; r < 4; r++){
            P[(size_t)(m0 + g*4 + r)*1024 + col] = acc[nf][r] + bs;
        }
    }
}

// --- node kernel: one wave per node, 4 edges in flight (16 lanes each) -------
__global__ __launch_bounds__(256) void node_k(
        const float* __restrict__ P, const float* __restrict__ vecs,
        const float* __restrict__ gvec, const float* __restrict__ frames,
        const int* __restrict__ start, const int* __restrict__ elist,
        const float* __restrict__ vprev, const float* __restrict__ gi_t,
        const float* __restrict__ bbi_t, float* __restrict__ out, int N){
    __shared__ float svs[4][4][100];   // [wave][sub][96 sv + pad]; sub stride 100
    int wv = threadIdx.x >> 6, ln = threadIdx.x & 63;
    int sub = ln >> 4, c = ln & 15;
    int n0 = blockIdx.x*4 + wv;
    int n = n0 < N ? n0 : N-1;

    // vi into every sub slot (elems 0..47)
    {
        const float* vc = vecs + (size_t)n*TV + c*3;
        svs[wv][sub][c*3+0] = vc[0];
        svs[wv][sub][c*3+1] = vc[1];
        svs[wv][sub][c*3+2] = vc[2];
    }
    float R[9];
    #pragma unroll
    for (int i = 0; i < 9; i++) R[i] = frames[(size_t)n*9 + i];

    float pa[32];
    {
        const float4* p4 = (const float4*)(P + (size_t)n*1024 + c*32);
        #pragma unroll
        for (int q = 0; q < 8; q++){
            float4 t = p4[q];
            pa[4*q+0]=t.x; pa[4*q+1]=t.y; pa[4*q+2]=t.z; pa[4*q+3]=t.w;
        }
    }
    int e0 = start[n], e1 = start[n+1];
    float a0 = 0.f, a1 = 0.f, a2 = 0.f;

    for (int t = e0 + sub; t < e1; t += 4){
        int row = elist[t];
        float l[32]; float s = 0.f, s2 = 0.f;
        {
            const float4* p4 = (const float4*)(P + (size_t)row*1024 + 512 + c*32);
            #pragma unroll
            for (int q = 0; q < 8; q++){
                float4 b = p4[q];
                float t0 = pa[4*q+0]+b.x, t1 = pa[4*q+1]+b.y;
                float t2v = pa[4*q+2]+b.z, t3 = pa[4*q+3]+b.w;
                l[4*q+0]=t0; l[4*q+1]=t1; l[4*q+2]=t2v; l[4*q+3]=t3;
                s += t0; s2 = fmaf(t0,t0,s2);
                s += t1; s2 = fmaf(t1,t1,s2);
                s += t2v; s2 = fmaf(t2v,t2v,s2);
                s += t3; s2 = fmaf(t3,t3,s2);
            }
        }
        #pragma unroll
        for (int off = 1; off < 16; off <<= 1){
            s  += __shfl_xor(s,  off, 64);
            s2 += __shfl_xor(s2, off, 64);
        }
        float mu  = s * (1.0f/NK);
        float var = fmaf(-mu, mu, s2 * (1.0f/NK));
        float inv = rsqrtf(var + 1e-5f);

        // vj_in_i for channel c: Ri^T @ gvec[row][c]  (write before sv reads)
        {
            const float* gr = gvec + (size_t)row*TV + c*3;
            float g0 = gr[0], g1 = gr[1], g2 = gr[2];
            svs[wv][sub][48+c*3+0] = R[0]*g0 + R[3]*g1 + R[6]*g2;
            svs[wv][sub][48+c*3+1] = R[1]*g0 + R[4]*g1 + R[7]*g2;
            svs[wv][sub][48+c*3+2] = R[2]*g0 + R[5]*g1 + R[8]*g2;
        }
        // weights overwrite l in place: w = sigmoid(g*(l-mu)*inv + b)
        //   gi_t/bbi_t pre-negated: w = 1/(1+__expf( gneg*z + bneg ))
        {
            const float4* g4 = (const float4*)(gi_t  + c*32);
            const float4* b4 = (const float4*)(bbi_t + c*32);
            #pragma unroll
            for (int q = 0; q < 8; q++){
                float4 gg = g4[q], bb = b4[q];
                float gx[4] = {gg.x, gg.y, gg.z, gg.w};
                float bx[4] = {bb.x, bb.y, bb.z, bb.w};
                #pragma unroll
                for (int r = 0; r < 4; r++){
                    float z = (l[4*q+r] - mu) * inv;
                    float yn = fmaf(gx[r], z, bx[r]);       // = -y
                    l[4*q+r] = 1.0f / (1.0f + __expf(yn));
                }
            }
        }
        // bilinear: acc[o] += sv[ch][o] * w[ch], 24 float4 LDS reads
        {
            const float4* sv4 = (const float4*)&svs[wv][sub][0];
            #pragma unroll
            for (int q = 0; q < 24; q++){
                float4 x = sv4[q];
                {   const int e = 4*q+0, ch = e/3, o = e%3;
                    float p = x.x * l[ch];
                    if (o==0) a0 += p; else if (o==1) a1 += p; else a2 += p; }
                {   const int e = 4*q+1, ch = e/3, o = e%3;
                    float p = x.y * l[ch];
                    if (o==0) a0 += p; else if (o==1) a1 += p; else a2 += p; }
                {   const int e = 4*q+2, ch = e/3, o = e%3;
                    float p = x.z * l[ch];
                    if (o==0) a0 += p; else if (o==1) a1 += p; else a2 += p; }
                {   const int e = 4*q+3, ch = e/3, o = e%3;
                    float p = x.w * l[ch];
                    if (o==0) a0 += p; else if (o==1) a1 += p; else a2 += p; }
            }
        }
    }
    a0 += __shfl_xor(a0,16,64); a0 += __shfl_xor(a0,32,64);
    a1 += __shfl_xor(a1,16,64); a1 += __shfl_xor(a1,32,64);
    a2 += __shfl_xor(a2,16,64); a2 += __shfl_xor(a2,32,64);
    if (ln < 16 && n0 < N){
        size_t o = (size_t)n*TV + c*3;
        out[o+0] = vprev[o+0] + a0;
        out[o+1] = vprev[o+1] + a1;
        out[o+2] = vprev[o+2] + a2;
    }
}

// ============================================================================
extern "C" void kernel_launch(void* const* d_in, const int* in_sizes, int n_in,
                              void* d_out, int out_size, void* d_ws, size_t ws_size,
                              hipStream_t stream){
    const float* h      = (const float*)d_in[1];
    const void*  eidx   = d_in[2];
    const float* frames = (const float*)d_in[3];
    const float* vprev  = (const float*)d_in[5];
    const float* W1  = (const float*)d_in[6];
    const float* b1  = (const float*)d_in[7];
    const float* g1  = (const float*)d_in[8];
    const float* bb1 = (const float*)d_in[9];
    const float* W2  = (const float*)d_in[10];
    const float* b2  = (const float*)d_in[11];
    const float* g2  = (const float*)d_in[12];
    const float* bb2 = (const float*)d_in[13];
    const float* Wi  = (const float*)d_in[14];
    const float* bi  = (const float*)d_in[15];
    const float* gi  = (const float*)d_in[16];
    const float* bbi = (const float*)d_in[17];
    float* out = (float*)d_out;

    const int N = in_sizes[1] / DD;
    const int E = in_sizes[2] / 2;
    const int Np = ((N + 63) / 64) * 64;

    // workspace carve-up
    float* bias_t = (float*)d_ws;                     // 1024
    float* gi_t   = bias_t + 1024;                    // 512
    float* bbi_t  = gi_t + 512;                       // 512
    float* vecs   = bbi_t + 512;                      // N*48
    float* gvec   = vecs + (size_t)N*TV;              // N*48
    unsigned short* Wtb = (unsigned short*)(gvec + (size_t)N*TV);  // 1024*128
    unsigned short* hbh = Wtb + 1024*128;             // Np*128
    unsigned short* hbl = hbh + (size_t)Np*128;       // Np*128
    int* idx32  = (int*)(hbl + (size_t)Np*128);       // 2E
    int* cnt    = idx32 + 2*(size_t)E;                // N
    int* startp = cnt + N;                            // N+1
    int* cursor = startp + N + 1;                     // N
    int* elist  = cursor + N;                         // E
    int* dflag  = elist + E;                          // 1
    uintptr_t pb = (uintptr_t)(dflag + 1);
    pb = (pb + 15) & ~(uintptr_t)15;
    float* P = (float*)pb;                            // Np*1024 fp32

    int nchk = E < 4096 ? E : 4096;
    detect_i64<<<1, 256, 0, stream>>>((const int*)eidx, nchk, dflag);
    zero_cnt<<<(N + 255)/256, 256, 0, stream>>>(cnt, N);
    cvt_hist<<<(2*E + 255)/256, 256, 0, stream>>>(eidx, idx32, cnt, 2*E, E, dflag);
    build_wt<<<1024, 128, 0, stream>>>(Wi, bi, gi, bbi, Wtb, bias_t, gi_t, bbi_t);
    cast_h<<<(Np*DD + 255)/256, 256, 0, stream>>>(h, hbh, hbl, N, Np*DD);
    vinit<<<(N + 3)/4, 256, 0, stream>>>(h, W1, b1, g1, bb1, W2, b2, g2, bb2,
                                         frames, vecs, gvec, N);
    gemm_mfma<<<dim3(4, Np/64), 256, 0, stream>>>(hbh, hbl, Wtb, bias_t, P, Np);
    scan_k<<<1, 1024, 0, stream>>>(cnt, startp, cursor, N);
    scatter_k<<<(E + 255)/256, 256, 0, stream>>>(idx32, cursor, elist, E);
    node_k<<<(N + 3)/4, 256, 0, stream>>>(P, vecs, gvec, frames, startp, elist,
                                          vprev, gi_t, bbi_t, out, N);
    (void)ws_size; (void)n_in; (void)out_size;
}

// Round 7
// 673.193 us; speedup vs baseline: 1.0877x; 1.0877x over previous
//
#include <hip/hip_runtime.h>

// ============================================================================
// VectorChannel, round 5 re-land #2 (broker timeouts): bf16 P + lean node_k.
//   logits[e] = PA[col] + PB[row]; P = (h_hi + h_lo) @ Wtb via bf16 MFMA,
//   stored bf16. k-packing inside MFMA operands is a shared bijection.
//   node_k: PA unpacked once/node; fused 2-moment LN; in-place weights;
//   float4 LDS bilinear. cast folded into vinit; detect+zero merged.
// ============================================================================

#define DD 128
#define VV 16
#define TV 48      // 3*V
#define NK 512     // 2*V*V

typedef __attribute__((ext_vector_type(8))) short short8;   // 8 bf16 (4 VGPR)
typedef __attribute__((ext_vector_type(4))) float f32x4;

__device__ __forceinline__ unsigned short f2bf(float f){
    union{float f; unsigned u;} v; v.f = f;
    unsigned r = v.u + 0x7fffu + ((v.u >> 16) & 1u);   // RTNE
    return (unsigned short)(r >> 16);
}
__device__ __forceinline__ float bf2f(unsigned short h){
    union{unsigned u; float f;} v; v.u = ((unsigned)h) << 16; return v.f;
}
__device__ __forceinline__ float bf2f_hi(unsigned u){
    union{unsigned u; float f;} v; v.u = u & 0xffff0000u; return v.f;
}
__device__ __forceinline__ float bf2f_lo(unsigned u){
    union{unsigned u; float f;} v; v.u = u << 16; return v.f;
}
__device__ __forceinline__ void unpack8(uint4 q, float* d){
    d[0]=bf2f_lo(q.x); d[1]=bf2f_hi(q.x);
    d[2]=bf2f_lo(q.y); d[3]=bf2f_hi(q.y);
    d[4]=bf2f_lo(q.z); d[5]=bf2f_hi(q.z);
    d[6]=bf2f_lo(q.w); d[7]=bf2f_hi(q.w);
}
__device__ __forceinline__ float waveRedSum64(float v){
    #pragma unroll
    for (int off = 32; off > 0; off >>= 1) v += __shfl_xor(v, off, 64);
    return v;
}

// --- zero cnt + detect int64 (block 0) ---------------------------------------
__global__ void prep_k(const int* __restrict__ p, int nchk, int* __restrict__ flag,
                       int* __restrict__ cnt, int N){
    int i = blockIdx.x*blockDim.x + threadIdx.x;
    if (i < N) cnt[i] = 0;
    if (blockIdx.x == 0){
        __shared__ int s;
        if (threadIdx.x == 0) s = 0;
        __syncthreads();
        int nz = 0;
        for (int k = threadIdx.x; k < nchk; k += blockDim.x) nz |= (p[2*k+1] != 0);
        if (nz) atomicOr(&s, 1);
        __syncthreads();
        if (threadIdx.x == 0) *flag = s ? 0 : 1;   // 1 => int64
    }
}

// convert indices to i32 AND histogram the cols
__global__ void cvt_hist(const void* __restrict__ src, int* __restrict__ dst,
                         int* __restrict__ cnt, int n, int E,
                         const int* __restrict__ flag){
    int i = blockIdx.x*blockDim.x + threadIdx.x;
    if (i >= n) return;
    int v = (*flag) ? (int)((const long long*)src)[i] : ((const int*)src)[i];
    dst[i] = v;
    if (i >= E) atomicAdd(&cnt[v], 1);   // i>=E => col array
}

// exclusive scan of cnt[N] -> start[N+1], cursor copy (1 block)
__global__ __launch_bounds__(1024) void scan_k(const int* __restrict__ cnt,
        int* __restrict__ start, int* __restrict__ cursor, int N){
    __shared__ int wsum[16];
    __shared__ int woff[16];
    __shared__ int btot;
    __shared__ int carry;
    int tid = threadIdx.x;
    int lane = tid & 63, wid = tid >> 6;
    if (tid == 0) carry = 0;
    __syncthreads();
    for (int base = 0; base < N; base += 1024){
        int i = base + tid;
        int x = (i < N) ? cnt[i] : 0;
        int v = x;
        #pragma unroll
        for (int off = 1; off < 64; off <<= 1){
            int t = __shfl_up(v, off, 64);
            if (lane >= off) v += t;
        }
        if (lane == 63) wsum[wid] = v;
        __syncthreads();
        if (wid == 0 && lane < 16){
            int s = wsum[lane];
            int sv = s;
            #pragma unroll
            for (int off = 1; off < 16; off <<= 1){
                int t = __shfl_up(sv, off, 64);
                if (lane >= off) sv += t;
            }
            woff[lane] = sv - s;
            if (lane == 15) btot = sv;
        }
        __syncthreads();
        if (i < N){
            int excl = v - x + woff[wid] + carry;
            start[i] = excl;
            cursor[i] = excl;
        }
        __syncthreads();
        if (tid == 0) carry += btot;
        __syncthreads();
    }
    if (tid == 0) start[N] = carry;
}

__global__ void scatter_k(const int* __restrict__ idx, int* __restrict__ cursor,
                          int* __restrict__ elist, int E){
    int e = blockIdx.x*blockDim.x + threadIdx.x;
    if (e >= E) return;
    int col = idx[E + e], row = idx[e];
    int pos = atomicAdd(&cursor[col], 1);
    elist[pos] = row;
}

// --- build permuted bf16 weight matrix [1024 cols][128 k] + params -----------
// col j<512: PA (c=j/32,kk=j%32 -> k=kk*16+c, Wi[k][0:128], bias bi[k])
//     j>=512: PB (Wi[k][128:256], bias 0). gi_t/bbi_t pre-negated for sigmoid.
__global__ void build_wt(const float* __restrict__ Wi, const float* __restrict__ bi,
                         const float* __restrict__ gi, const float* __restrict__ bbi,
                         unsigned short* __restrict__ Wtb, float* __restrict__ bias_t,
                         float* __restrict__ gi_t, float* __restrict__ bbi_t){
    int j = blockIdx.x;        // 0..1023
    int d = threadIdx.x;       // 0..127
    int half = j >> 9;
    int jj = j & 511;
    int c = jj >> 5, kk = jj & 31;
    int k = kk*16 + c;
    Wtb[(size_t)j*128 + d] = f2bf(Wi[k*256 + half*128 + d]);
    if (d == 0){
        bias_t[j] = half ? 0.0f : bi[k];
        if (!half){ gi_t[jj] = -gi[k]; bbi_t[jj] = -bbi[k]; }   // negated
    }
}

// --- vector_init (+ h split to bf16 hi/lo, folded) ---------------------------
__global__ __launch_bounds__(256) void vinit(
        const float* __restrict__ h,
        const float* __restrict__ W1, const float* __restrict__ b1,
        const float* __restrict__ g1, const float* __restrict__ bb1,
        const float* __restrict__ W2, const float* __restrict__ b2,
        const float* __restrict__ g2, const float* __restrict__ bb2,
        const float* __restrict__ frames,
        float* __restrict__ vecs, float* __restrict__ gvec,
        unsigned short* __restrict__ hbh, unsigned short* __restrict__ hbl, int N){
    __shared__ float hs[4][DD];
    __shared__ float ts[4][TV];
    int w = threadIdx.x >> 6, l = threadIdx.x & 63;
    int n = blockIdx.x*4 + w;
    int nr = n < N ? n : N-1;
    float hv0 = h[(size_t)nr*DD + l];
    float hv1 = h[(size_t)nr*DD + 64 + l];
    hs[w][l]      = hv0;
    hs[w][l + 64] = hv1;
    if (n < N){     // folded cast_h: split to bf16 hi/lo
        unsigned short h0 = f2bf(hv0), h1 = f2bf(hv1);
        hbh[(size_t)n*DD + l]      = h0;
        hbh[(size_t)n*DD + 64 + l] = h1;
        hbl[(size_t)n*DD + l]      = f2bf(hv0 - bf2f(h0));
        hbl[(size_t)n*DD + 64 + l] = f2bf(hv1 - bf2f(h1));
    }
    __syncthreads();

    float o1 = 0.0f;
    if (l < TV){
        o1 = b1[l];
        const float* wr = W1 + l*DD;
        #pragma unroll
        for (int d = 0; d < DD; d += 4){
            float4 w4 = *(const float4*)(wr + d);
            o1 += hs[w][d]*w4.x + hs[w][d+1]*w4.y + hs[w][d+2]*w4.z + hs[w][d+3]*w4.w;
        }
    }
    float s  = waveRedSum64(l < TV ? o1 : 0.0f);
    float mu = s * (1.0f/TV);
    float dv = l < TV ? (o1 - mu) : 0.0f;
    float sq = waveRedSum64(dv*dv);
    float inv = rsqrtf(sq*(1.0f/TV) + 1e-5f);
    if (l < TV){
        float y = g1[l]*(dv*inv) + bb1[l];
        ts[w][l] = y / (1.0f + __expf(-y));
    }
    __syncthreads();

    float o2 = 0.0f;
    if (l < TV){
        o2 = b2[l];
        const float* wr = W2 + l*TV;
        #pragma unroll
        for (int j = 0; j < TV; j += 4){
            float4 w4 = *(const float4*)(wr + j);
            o2 += ts[w][j]*w4.x + ts[w][j+1]*w4.y + ts[w][j+2]*w4.z + ts[w][j+3]*w4.w;
        }
    }
    s  = waveRedSum64(l < TV ? o2 : 0.0f);
    mu = s * (1.0f/TV);
    dv = l < TV ? (o2 - mu) : 0.0f;
    sq = waveRedSum64(dv*dv);
    inv = rsqrtf(sq*(1.0f/TV) + 1e-5f);
    __syncthreads();
    if (l < TV){
        float y = g2[l]*(dv*inv) + bb2[l];
        float t2 = y / (1.0f + __expf(-y));
        if (n < N) vecs[(size_t)n*TV + l] = t2;
        ts[w][l] = t2;
    }
    __syncthreads();
    if (l < TV && n < N){
        int cc = l/3, oo = l%3;  // g[n][cc][oo] = sum_j R[oo][j]*v[cc][j]
        const float* R = frames + (size_t)n*9;
        float gv = R[oo*3+0]*ts[w][cc*3+0] + R[oo*3+1]*ts[w][cc*3+1] + R[oo*3+2]*ts[w][cc*3+2];
        gvec[(size_t)n*TV + l] = gv;
    }
}

// --- P = (h_hi + h_lo) @ Wtb^T + bias : bf16 MFMA, bf16 out ------------------
// Wave: 16 rows x 256 cols. A/B k-packing: elems 0-3 <- k=kb..kb+3,
// elems 4-7 <- k=kb+16..kb+19, kb = ks + 4*(lane>>4): shared bijection.
// C/D: col=lane&15, row=(lane>>4)*4+reg  [m89-verified].
__global__ __launch_bounds__(256) void gemm_mfma(
        const unsigned short* __restrict__ hbh, const unsigned short* __restrict__ hbl,
        const unsigned short* __restrict__ Wtb, const float* __restrict__ bias_t,
        unsigned short* __restrict__ P, int Np){
    int wv = threadIdx.x >> 6, l = threadIdx.x & 63;
    int lr = l & 15, g = l >> 4;
    int m0 = (blockIdx.y*4 + wv)*16;
    int n0 = blockIdx.x*256;

    f32x4 acc[16];
    #pragma unroll
    for (int nf = 0; nf < 16; nf++) acc[nf] = (f32x4){0.f,0.f,0.f,0.f};

    const unsigned short* arow_h = hbh + (size_t)(m0 + lr)*128;
    const unsigned short* arow_l = hbl + (size_t)(m0 + lr)*128;

    #pragma unroll
    for (int ks = 0; ks < 128; ks += 32){
        int kb = ks + 4*g;
        short8 ah, al;
        ((ushort4*)&ah)[0] = *(const ushort4*)(arow_h + kb);
        ((ushort4*)&ah)[1] = *(const ushort4*)(arow_h + kb + 16);
        ((ushort4*)&al)[0] = *(const ushort4*)(arow_l + kb);
        ((ushort4*)&al)[1] = *(const ushort4*)(arow_l + kb + 16);
        #pragma unroll
        for (int nf = 0; nf < 16; nf++){
            const unsigned short* brow = Wtb + (size_t)(n0 + nf*16 + lr)*128;
            short8 b;
            ((ushort4*)&b)[0] = *(const ushort4*)(brow + kb);
            ((ushort4*)&b)[1] = *(const ushort4*)(brow + kb + 16);
            acc[nf] = __builtin_amdgcn_mfma_f32_16x16x32_bf16(ah, b, acc[nf], 0, 0, 0);
            acc[nf] = __builtin_amdgcn_mfma_f32_16x16x32_bf16(al, b, acc[nf], 0, 0, 0);
        }
    }
    #pragma unroll
    for (int nf = 0; nf < 16; nf++){
        int col = n0 + nf*16 + lr;
        float bs = bias_t[col];
        #pragma unroll
        for (int r = 0; r < 4; r++){
            P[(size_t)(m0 + g*4 + r)*1024 + col] = f2bf(acc[nf][r] + bs);
        }
    }
}

// --- node kernel: one wave per node, 4 edges in flight (16 lanes each) -------
__global__ __launch_bounds__(256) void node_k(
        const unsigned short* __restrict__ P, const float* __restrict__ vecs,
        const float* __restrict__ gvec, const float* __restrict__ frames,
        const int* __restrict__ start, const int* __restrict__ elist,
        const float* __restrict__ vprev, const float* __restrict__ gi_t,
        const float* __restrict__ bbi_t, float* __restrict__ out, int N){
    __shared__ float svs[4][4][100];   // [wave][sub][48 vi + 48 vj + pad]
    int wv = threadIdx.x >> 6, ln = threadIdx.x & 63;
    int sub = ln >> 4, c = ln & 15;
    int n0 = blockIdx.x*4 + wv;
    int n = n0 < N ? n0 : N-1;

    {   // vi into every sub slot
        const float* vc = vecs + (size_t)n*TV + c*3;
        svs[wv][sub][c*3+0] = vc[0];
        svs[wv][sub][c*3+1] = vc[1];
        svs[wv][sub][c*3+2] = vc[2];
    }
    float R[9];
    #pragma unroll
    for (int i = 0; i < 9; i++) R[i] = frames[(size_t)n*9 + i];

    float pa[32];          // PA unpacked once per node
    {
        const uint4* p4 = (const uint4*)(P + (size_t)n*1024 + c*32);
        #pragma unroll
        for (int q = 0; q < 4; q++) unpack8(p4[q], pa + 8*q);
    }
    int e0 = start[n], e1 = start[n+1];
    float a0 = 0.f, a1 = 0.f, a2 = 0.f;

    for (int t = e0 + sub; t < e1; t += 4){
        int row = elist[t];
        float l[32]; float s = 0.f, s2 = 0.f;
        {
            const uint4* p4 = (const uint4*)(P + (size_t)row*1024 + 512 + c*32);
            #pragma unroll
            for (int q = 0; q < 4; q++){
                float tmp[8]; unpack8(p4[q], tmp);
                #pragma unroll
                for (int r = 0; r < 8; r++){
                    float x = pa[8*q+r] + tmp[r];
                    l[8*q+r] = x;
                    s += x; s2 = fmaf(x, x, s2);
                }
            }
        }
        #pragma unroll
        for (int off = 1; off < 16; off <<= 1){
            s  += __shfl_xor(s,  off, 64);
            s2 += __shfl_xor(s2, off, 64);
        }
        float mu  = s * (1.0f/NK);
        float var = fmaf(-mu, mu, s2 * (1.0f/NK));
        float inv = rsqrtf(var + 1e-5f);

        // vj_in_i for channel c: Ri^T @ gvec[row][c]
        {
            const float* gr = gvec + (size_t)row*TV + c*3;
            float g0 = gr[0], g1 = gr[1], g2 = gr[2];
            svs[wv][sub][48+c*3+0] = R[0]*g0 + R[3]*g1 + R[6]*g2;
            svs[wv][sub][48+c*3+1] = R[1]*g0 + R[4]*g1 + R[7]*g2;
            svs[wv][sub][48+c*3+2] = R[2]*g0 + R[5]*g1 + R[8]*g2;
        }
        // weights in place: gi_t/bbi_t pre-negated -> w = 1/(1+exp(gneg*z+bneg))
        {
            const float4* g4 = (const float4*)(gi_t  + c*32);
            const float4* b4 = (const float4*)(bbi_t + c*32);
            #pragma unroll
            for (int q = 0; q < 8; q++){
                float4 gg = g4[q], bb = b4[q];
                float gx[4] = {gg.x, gg.y, gg.z, gg.w};
                float bx[4] = {bb.x, bb.y, bb.z, bb.w};
                #pragma unroll
                for (int r = 0; r < 4; r++){
                    float z = (l[4*q+r] - mu) * inv;
                    float yn = fmaf(gx[r], z, bx[r]);       // = -y
                    l[4*q+r] = 1.0f / (1.0f + __expf(yn));
                }
            }
        }
        // bilinear: acc[o] += sv[ch][o] * w[ch], 24 float4 LDS reads
        {
            const float4* sv4 = (const float4*)&svs[wv][sub][0];
            #pragma unroll
            for (int q = 0; q < 24; q++){
                float4 x = sv4[q];
                {   const int e = 4*q+0, ch = e/3, o = e%3;
                    float p = x.x * l[ch];
                    if (o==0) a0 += p; else if (o==1) a1 += p; else a2 += p; }
                {   const int e = 4*q+1, ch = e/3, o = e%3;
                    float p = x.y * l[ch];
                    if (o==0) a0 += p; else if (o==1) a1 += p; else a2 += p; }
                {   const int e = 4*q+2, ch = e/3, o = e%3;
                    float p = x.z * l[ch];
                    if (o==0) a0 += p; else if (o==1) a1 += p; else a2 += p; }
                {   const int e = 4*q+3, ch = e/3, o = e%3;
                    float p = x.w * l[ch];
                    if (o==0) a0 += p; else if (o==1) a1 += p; else a2 += p; }
            }
        }
    }
    a0 += __shfl_xor(a0,16,64); a0 += __shfl_xor(a0,32,64);
    a1 += __shfl_xor(a1,16,64); a1 += __shfl_xor(a1,32,64);
    a2 += __shfl_xor(a2,16,64); a2 += __shfl_xor(a2,32,64);
    if (ln < 16 && n0 < N){
        size_t o = (size_t)n*TV + c*3;
        out[o+0] = vprev[o+0] + a0;
        out[o+1] = vprev[o+1] + a1;
        out[o+2] = vprev[o+2] + a2;
    }
}

// ============================================================================
extern "C" void kernel_launch(void* const* d_in, const int* in_sizes, int n_in,
                              void* d_out, int out_size, void* d_ws, size_t ws_size,
                              hipStream_t stream){
    const float* h      = (const float*)d_in[1];
    const void*  eidx   = d_in[2];
    const float* frames = (const float*)d_in[3];
    const float* vprev  = (const float*)d_in[5];
    const float* W1  = (const float*)d_in[6];
    const float* b1  = (const float*)d_in[7];
    const float* g1  = (const float*)d_in[8];
    const float* bb1 = (const float*)d_in[9];
    const float* W2  = (const float*)d_in[10];
    const float* b2  = (const float*)d_in[11];
    const float* g2  = (const float*)d_in[12];
    const float* bb2 = (const float*)d_in[13];
    const float* Wi  = (const float*)d_in[14];
    const float* bi  = (const float*)d_in[15];
    const float* gi  = (const float*)d_in[16];
    const float* bbi = (const float*)d_in[17];
    float* out = (float*)d_out;

    const int N = in_sizes[1] / DD;
    const int E = in_sizes[2] / 2;
    const int Np = ((N + 63) / 64) * 64;

    // workspace carve-up
    float* bias_t = (float*)d_ws;                     // 1024
    float* gi_t   = bias_t + 1024;                    // 512
    float* bbi_t  = gi_t + 512;                       // 512
    float* vecs   = bbi_t + 512;                      // N*48
    float* gvec   = vecs + (size_t)N*TV;              // N*48
    unsigned short* Wtb = (unsigned short*)(gvec + (size_t)N*TV);  // 1024*128
    unsigned short* hbh = Wtb + 1024*128;             // Np*128
    unsigned short* hbl = hbh + (size_t)Np*128;       // Np*128
    unsigned short* P   = hbl + (size_t)Np*128;       // Np*1024 bf16
    int* idx32  = (int*)(P + (size_t)Np*1024);        // 2E
    int* cnt    = idx32 + 2*(size_t)E;                // N
    int* startp = cnt + N;                            // N+1
    int* cursor = startp + N + 1;                     // N
    int* elist  = cursor + N;                         // E
    int* dflag  = elist + E;                          // 1

    int nchk = E < 4096 ? E : 4096;
    prep_k<<<(N + 255)/256, 256, 0, stream>>>((const int*)eidx, nchk, dflag, cnt, N);
    cvt_hist<<<(2*E + 255)/256, 256, 0, stream>>>(eidx, idx32, cnt, 2*E, E, dflag);
    build_wt<<<1024, 128, 0, stream>>>(Wi, bi, gi, bbi, Wtb, bias_t, gi_t, bbi_t);
    vinit<<<(N + 3)/4, 256, 0, stream>>>(h, W1, b1, g1, bb1, W2, b2, g2, bb2,
                                         frames, vecs, gvec, hbh, hbl, N);
    gemm_mfma<<<dim3(4, Np/64), 256, 0, stream>>>(hbh, hbl, Wtb, bias_t, P, Np);
    scan_k<<<1, 1024, 0, stream>>>(cnt, startp, cursor, N);
    scatter_k<<<(E + 255)/256, 256, 0, stream>>>(idx32, cursor, elist, E);
    node_k<<<(N + 3)/4, 256, 0, stream>>>(P, vecs, gvec, frames, startp, elist,
                                          vprev, gi_t, bbi_t, out, N);
    (void)ws_size; (void)n_in; (void)out_size;
}

// Round 10
// 582.070 us; speedup vs baseline: 1.2580x; 1.1566x over previous
//
#include <hip/hip_runtime.h>

// ============================================================================
// VectorChannel, round 8 re-land #3 (broker timeouts): pipelined node_k + lean
// sigmoid. node_k was gather-LATENCY-bound (798GB/s=10% peak, stall 148us of
// 311us): 1-deep pipeline issues edge t+4's PB/gvec loads before computing
// edge t. Sigmoid: z=fma(l,inv,nmi); arg=fma(-g*log2e, z, -b*log2e);
// w = rcp(1 + exp2(arg)) -> 5 inst/elem incl 2 trans (was ~8).
// ============================================================================

#define DD 128
#define VV 16
#define TV 48      // 3*V
#define NK 512     // 2*V*V
#define LOG2E 1.44269504088896340736f

typedef __attribute__((ext_vector_type(8))) short short8;   // 8 bf16 (4 VGPR)
typedef __attribute__((ext_vector_type(4))) float f32x4;

#if __has_builtin(__builtin_amdgcn_exp2f)
#define EXP2F(x) __builtin_amdgcn_exp2f(x)
#else
#define EXP2F(x) exp2f(x)
#endif
#if __has_builtin(__builtin_amdgcn_rcpf)
#define RCPF(x) __builtin_amdgcn_rcpf(x)
#else
#define RCPF(x) (1.0f/(x))
#endif

__device__ __forceinline__ unsigned short f2bf(float f){
    union{float f; unsigned u;} v; v.f = f;
    unsigned r = v.u + 0x7fffu + ((v.u >> 16) & 1u);   // RTNE
    return (unsigned short)(r >> 16);
}
__device__ __forceinline__ float bf2f(unsigned short h){
    union{unsigned u; float f;} v; v.u = ((unsigned)h) << 16; return v.f;
}
__device__ __forceinline__ float bf2f_hi(unsigned u){
    union{unsigned u; float f;} v; v.u = u & 0xffff0000u; return v.f;
}
__device__ __forceinline__ float bf2f_lo(unsigned u){
    union{unsigned u; float f;} v; v.u = u << 16; return v.f;
}
__device__ __forceinline__ void unpack8(uint4 q, float* d){
    d[0]=bf2f_lo(q.x); d[1]=bf2f_hi(q.x);
    d[2]=bf2f_lo(q.y); d[3]=bf2f_hi(q.y);
    d[4]=bf2f_lo(q.z); d[5]=bf2f_hi(q.z);
    d[6]=bf2f_lo(q.w); d[7]=bf2f_hi(q.w);
}
__device__ __forceinline__ float waveRedSum64(float v){
    #pragma unroll
    for (int off = 32; off > 0; off >>= 1) v += __shfl_xor(v, off, 64);
    return v;
}

// --- zero cnt + detect int64 (block 0) ---------------------------------------
__global__ void prep_k(const int* __restrict__ p, int nchk, int* __restrict__ flag,
                       int* __restrict__ cnt, int N){
    int i = blockIdx.x*blockDim.x + threadIdx.x;
    if (i < N) cnt[i] = 0;
    if (blockIdx.x == 0){
        __shared__ int s;
        if (threadIdx.x == 0) s = 0;
        __syncthreads();
        int nz = 0;
        for (int k = threadIdx.x; k < nchk; k += blockDim.x) nz |= (p[2*k+1] != 0);
        if (nz) atomicOr(&s, 1);
        __syncthreads();
        if (threadIdx.x == 0) *flag = s ? 0 : 1;   // 1 => int64
    }
}

// convert indices to i32 AND histogram the cols
__global__ void cvt_hist(const void* __restrict__ src, int* __restrict__ dst,
                         int* __restrict__ cnt, int n, int E,
                         const int* __restrict__ flag){
    int i = blockIdx.x*blockDim.x + threadIdx.x;
    if (i >= n) return;
    int v = (*flag) ? (int)((const long long*)src)[i] : ((const int*)src)[i];
    dst[i] = v;
    if (i >= E) atomicAdd(&cnt[v], 1);   // i>=E => col array
}

// exclusive scan of cnt[N] -> start[N+1], cursor copy (1 block)
__global__ __launch_bounds__(1024) void scan_k(const int* __restrict__ cnt,
        int* __restrict__ start, int* __restrict__ cursor, int N){
    __shared__ int wsum[16];
    __shared__ int woff[16];
    __shared__ int btot;
    __shared__ int carry;
    int tid = threadIdx.x;
    int lane = tid & 63, wid = tid >> 6;
    if (tid == 0) carry = 0;
    __syncthreads();
    for (int base = 0; base < N; base += 1024){
        int i = base + tid;
        int x = (i < N) ? cnt[i] : 0;
        int v = x;
        #pragma unroll
        for (int off = 1; off < 64; off <<= 1){
            int t = __shfl_up(v, off, 64);
            if (lane >= off) v += t;
        }
        if (lane == 63) wsum[wid] = v;
        __syncthreads();
        if (wid == 0 && lane < 16){
            int s = wsum[lane];
            int sv = s;
            #pragma unroll
            for (int off = 1; off < 16; off <<= 1){
                int t = __shfl_up(sv, off, 64);
                if (lane >= off) sv += t;
            }
            woff[lane] = sv - s;
            if (lane == 15) btot = sv;
        }
        __syncthreads();
        if (i < N){
            int excl = v - x + woff[wid] + carry;
            start[i] = excl;
            cursor[i] = excl;
        }
        __syncthreads();
        if (tid == 0) carry += btot;
        __syncthreads();
    }
    if (tid == 0) start[N] = carry;
}

__global__ void scatter_k(const int* __restrict__ idx, int* __restrict__ cursor,
                          int* __restrict__ elist, int E){
    int e = blockIdx.x*blockDim.x + threadIdx.x;
    if (e >= E) return;
    int col = idx[E + e], row = idx[e];
    int pos = atomicAdd(&cursor[col], 1);
    elist[pos] = row;
}

// --- build permuted bf16 weight matrix [1024 cols][128 k] + params -----------
// col j<512: PA (c=j/32,kk=j%32 -> k=kk*16+c, Wi[k][0:128], bias bi[k])
//     j>=512: PB (Wi[k][128:256], bias 0).
// gi_t/bbi_t pre-scaled by -log2e for the exp2-form sigmoid.
__global__ void build_wt(const float* __restrict__ Wi, const float* __restrict__ bi,
                         const float* __restrict__ gi, const float* __restrict__ bbi,
                         unsigned short* __restrict__ Wtb, float* __restrict__ bias_t,
                         float* __restrict__ gi_t, float* __restrict__ bbi_t){
    int j = blockIdx.x;        // 0..1023
    int d = threadIdx.x;       // 0..127
    int half = j >> 9;
    int jj = j & 511;
    int c = jj >> 5, kk = jj & 31;
    int k = kk*16 + c;
    Wtb[(size_t)j*128 + d] = f2bf(Wi[k*256 + half*128 + d]);
    if (d == 0){
        bias_t[j] = half ? 0.0f : bi[k];
        if (!half){ gi_t[jj] = -gi[k]*LOG2E; bbi_t[jj] = -bbi[k]*LOG2E; }
    }
}

// --- vector_init (+ h split to bf16 hi/lo, folded) ---------------------------
__global__ __launch_bounds__(256) void vinit(
        const float* __restrict__ h,
        const float* __restrict__ W1, const float* __restrict__ b1,
        const float* __restrict__ g1, const float* __restrict__ bb1,
        const float* __restrict__ W2, const float* __restrict__ b2,
        const float* __restrict__ g2, const float* __restrict__ bb2,
        const float* __restrict__ frames,
        float* __restrict__ vecs, float* __restrict__ gvec,
        unsigned short* __restrict__ hbh, unsigned short* __restrict__ hbl, int N){
    __shared__ float hs[4][DD];
    __shared__ float ts[4][TV];
    int w = threadIdx.x >> 6, l = threadIdx.x & 63;
    int n = blockIdx.x*4 + w;
    int nr = n < N ? n : N-1;
    float hv0 = h[(size_t)nr*DD + l];
    float hv1 = h[(size_t)nr*DD + 64 + l];
    hs[w][l]      = hv0;
    hs[w][l + 64] = hv1;
    if (n < N){     // folded cast_h: split to bf16 hi/lo
        unsigned short h0 = f2bf(hv0), h1 = f2bf(hv1);
        hbh[(size_t)n*DD + l]      = h0;
        hbh[(size_t)n*DD + 64 + l] = h1;
        hbl[(size_t)n*DD + l]      = f2bf(hv0 - bf2f(h0));
        hbl[(size_t)n*DD + 64 + l] = f2bf(hv1 - bf2f(h1));
    }
    __syncthreads();

    float o1 = 0.0f;
    if (l < TV){
        o1 = b1[l];
        const float* wr = W1 + l*DD;
        #pragma unroll
        for (int d = 0; d < DD; d += 4){
            float4 w4 = *(const float4*)(wr + d);
            o1 += hs[w][d]*w4.x + hs[w][d+1]*w4.y + hs[w][d+2]*w4.z + hs[w][d+3]*w4.w;
        }
    }
    float s  = waveRedSum64(l < TV ? o1 : 0.0f);
    float mu = s * (1.0f/TV);
    float dv = l < TV ? (o1 - mu) : 0.0f;
    float sq = waveRedSum64(dv*dv);
    float inv = rsqrtf(sq*(1.0f/TV) + 1e-5f);
    if (l < TV){
        float y = g1[l]*(dv*inv) + bb1[l];
        ts[w][l] = y / (1.0f + __expf(-y));
    }
    __syncthreads();

    float o2 = 0.0f;
    if (l < TV){
        o2 = b2[l];
        const float* wr = W2 + l*TV;
        #pragma unroll
        for (int j = 0; j < TV; j += 4){
            float4 w4 = *(const float4*)(wr + j);
            o2 += ts[w][j]*w4.x + ts[w][j+1]*w4.y + ts[w][j+2]*w4.z + ts[w][j+3]*w4.w;
        }
    }
    s  = waveRedSum64(l < TV ? o2 : 0.0f);
    mu = s * (1.0f/TV);
    dv = l < TV ? (o2 - mu) : 0.0f;
    sq = waveRedSum64(dv*dv);
    inv = rsqrtf(sq*(1.0f/TV) + 1e-5f);
    __syncthreads();
    if (l < TV){
        float y = g2[l]*(dv*inv) + bb2[l];
        float t2 = y / (1.0f + __expf(-y));
        if (n < N) vecs[(size_t)n*TV + l] = t2;
        ts[w][l] = t2;
    }
    __syncthreads();
    if (l < TV && n < N){
        int cc = l/3, oo = l%3;  // g[n][cc][oo] = sum_j R[oo][j]*v[cc][j]
        const float* R = frames + (size_t)n*9;
        float gv = R[oo*3+0]*ts[w][cc*3+0] + R[oo*3+1]*ts[w][cc*3+1] + R[oo*3+2]*ts[w][cc*3+2];
        gvec[(size_t)n*TV + l] = gv;
    }
}

// --- P = (h_hi + h_lo) @ Wtb^T + bias : bf16 MFMA, bf16 out ------------------
__global__ __launch_bounds__(256) void gemm_mfma(
        const unsigned short* __restrict__ hbh, const unsigned short* __restrict__ hbl,
        const unsigned short* __restrict__ Wtb, const float* __restrict__ bias_t,
        unsigned short* __restrict__ P, int Np){
    int wv = threadIdx.x >> 6, l = threadIdx.x & 63;
    int lr = l & 15, g = l >> 4;
    int m0 = (blockIdx.y*4 + wv)*16;
    int n0 = blockIdx.x*256;

    f32x4 acc[16];
    #pragma unroll
    for (int nf = 0; nf < 16; nf++) acc[nf] = (f32x4){0.f,0.f,0.f,0.f};

    const unsigned short* arow_h = hbh + (size_t)(m0 + lr)*128;
    const unsigned short* arow_l = hbl + (size_t)(m0 + lr)*128;

    #pragma unroll
    for (int ks = 0; ks < 128; ks += 32){
        int kb = ks + 4*g;
        short8 ah, al;
        ((ushort4*)&ah)[0] = *(const ushort4*)(arow_h + kb);
        ((ushort4*)&ah)[1] = *(const ushort4*)(arow_h + kb + 16);
        ((ushort4*)&al)[0] = *(const ushort4*)(arow_l + kb);
        ((ushort4*)&al)[1] = *(const ushort4*)(arow_l + kb + 16);
        #pragma unroll
        for (int nf = 0; nf < 16; nf++){
            const unsigned short* brow = Wtb + (size_t)(n0 + nf*16 + lr)*128;
            short8 b;
            ((ushort4*)&b)[0] = *(const ushort4*)(brow + kb);
            ((ushort4*)&b)[1] = *(const ushort4*)(brow + kb + 16);
            acc[nf] = __builtin_amdgcn_mfma_f32_16x16x32_bf16(ah, b, acc[nf], 0, 0, 0);
            acc[nf] = __builtin_amdgcn_mfma_f32_16x16x32_bf16(al, b, acc[nf], 0, 0, 0);
        }
    }
    #pragma unroll
    for (int nf = 0; nf < 16; nf++){
        int col = n0 + nf*16 + lr;
        float bs = bias_t[col];
        #pragma unroll
        for (int r = 0; r < 4; r++){
            P[(size_t)(m0 + g*4 + r)*1024 + col] = f2bf(acc[nf][r] + bs);
        }
    }
}

// --- node kernel: one wave/node, 4 edges in flight, 1-deep load pipeline -----
__global__ __launch_bounds__(256) void node_k(
        const unsigned short* __restrict__ P, const float* __restrict__ vecs,
        const float* __restrict__ gvec, const float* __restrict__ frames,
        const int* __restrict__ start, const int* __restrict__ elist,
        const float* __restrict__ vprev, const float* __restrict__ gi_t,
        const float* __restrict__ bbi_t, float* __restrict__ out, int N){
    __shared__ float svs[4][4][100];   // [wave][sub][48 vi + 48 vj + pad]
    int wv = threadIdx.x >> 6, ln = threadIdx.x & 63;
    int sub = ln >> 4, c = ln & 15;
    int n0 = blockIdx.x*4 + wv;
    int n = n0 < N ? n0 : N-1;

    {   // vi into every sub slot
        const float* vc = vecs + (size_t)n*TV + c*3;
        svs[wv][sub][c*3+0] = vc[0];
        svs[wv][sub][c*3+1] = vc[1];
        svs[wv][sub][c*3+2] = vc[2];
    }
    float R[9];
    #pragma unroll
    for (int i = 0; i < 9; i++) R[i] = frames[(size_t)n*9 + i];

    float pa[32];          // PA unpacked once per node
    {
        const uint4* p4 = (const uint4*)(P + (size_t)n*1024 + c*32);
        #pragma unroll
        for (int q = 0; q < 4; q++) unpack8(p4[q], pa + 8*q);
    }
    int e0 = start[n], e1 = start[n+1];
    float a0 = 0.f, a1 = 0.f, a2 = 0.f;

    // ---- pipeline prologue: load edge t's PB + gvec (clamped-safe) ----
    int t = e0 + sub;
    int rcur = elist[t < e1 ? t : 0];
    uint4 pb0, pb1, pb2, pb3;
    float gv0, gv1, gv2;
    {
        const uint4* p4 = (const uint4*)(P + (size_t)rcur*1024 + 512 + c*32);
        pb0 = p4[0]; pb1 = p4[1]; pb2 = p4[2]; pb3 = p4[3];
        const float* gr = gvec + (size_t)rcur*TV + c*3;
        gv0 = gr[0]; gv1 = gr[1]; gv2 = gr[2];
    }

    for (; t < e1; t += 4){
        // ---- issue NEXT edge's loads before computing current ----
        int tn = t + 4;
        int rnext = elist[tn < e1 ? tn : 0];
        uint4 nb0, nb1, nb2, nb3;
        float ng0, ng1, ng2;
        {
            const uint4* p4 = (const uint4*)(P + (size_t)rnext*1024 + 512 + c*32);
            nb0 = p4[0]; nb1 = p4[1]; nb2 = p4[2]; nb3 = p4[3];
            const float* gr = gvec + (size_t)rnext*TV + c*3;
            ng0 = gr[0]; ng1 = gr[1]; ng2 = gr[2];
        }

        // ---- compute current edge from registers ----
        float l[32];
        unpack8(pb0, l+0); unpack8(pb1, l+8); unpack8(pb2, l+16); unpack8(pb3, l+24);
        float sA = 0.f, sB = 0.f, qA = 0.f, qB = 0.f;
        #pragma unroll
        for (int i = 0; i < 16; i++){
            float xa = pa[i]    + l[i];    l[i]    = xa; sA += xa; qA = fmaf(xa, xa, qA);
            float xb = pa[16+i] + l[16+i]; l[16+i] = xb; sB += xb; qB = fmaf(xb, xb, qB);
        }
        float s = sA + sB, sq = qA + qB;
        #pragma unroll
        for (int off = 1; off < 16; off <<= 1){
            s  += __shfl_xor(s,  off, 64);
            sq += __shfl_xor(sq, off, 64);
        }
        float mu  = s * (1.0f/NK);
        float var = fmaf(-mu, mu, sq * (1.0f/NK));
        float inv = rsqrtf(var + 1e-5f);
        float nmi = -mu * inv;

        // vj_in_i for channel c: Ri^T @ gvec[row][c]
        svs[wv][sub][48+c*3+0] = R[0]*gv0 + R[3]*gv1 + R[6]*gv2;
        svs[wv][sub][48+c*3+1] = R[1]*gv0 + R[4]*gv1 + R[7]*gv2;
        svs[wv][sub][48+c*3+2] = R[2]*gv0 + R[5]*gv1 + R[8]*gv2;

        // weights in place: w = rcp(1 + exp2(fma(g2, z, b2))), z = fma(l,inv,nmi)
        {
            const float4* g4 = (const float4*)(gi_t  + c*32);
            const float4* b4 = (const float4*)(bbi_t + c*32);
            #pragma unroll
            for (int q = 0; q < 8; q++){
                float4 gg = g4[q], bb = b4[q];
                float gx[4] = {gg.x, gg.y, gg.z, gg.w};
                float bx[4] = {bb.x, bb.y, bb.z, bb.w};
                #pragma unroll
                for (int r = 0; r < 4; r++){
                    float z   = fmaf(l[4*q+r], inv, nmi);
                    float arg = fmaf(gx[r], z, bx[r]);
                    l[4*q+r]  = RCPF(1.0f + EXP2F(arg));
                }
            }
        }
        // bilinear: acc[o] += sv[ch][o] * w[ch], 24 float4 LDS reads
        {
            const float4* sv4 = (const float4*)&svs[wv][sub][0];
            #pragma unroll
            for (int q = 0; q < 24; q++){
                float4 x = sv4[q];
                {   const int e = 4*q+0, ch = e/3, o = e%3;
                    float p = x.x * l[ch];
                    if (o==0) a0 += p; else if (o==1) a1 += p; else a2 += p; }
                {   const int e = 4*q+1, ch = e/3, o = e%3;
                    float p = x.y * l[ch];
                    if (o==0) a0 += p; else if (o==1) a1 += p; else a2 += p; }
                {   const int e = 4*q+2, ch = e/3, o = e%3;
                    float p = x.z * l[ch];
                    if (o==0) a0 += p; else if (o==1) a1 += p; else a2 += p; }
                {   const int e = 4*q+3, ch = e/3, o = e%3;
                    float p = x.w * l[ch];
                    if (o==0) a0 += p; else if (o==1) a1 += p; else a2 += p; }
            }
        }
        // ---- rotate pipeline registers ----
        pb0 = nb0; pb1 = nb1; pb2 = nb2; pb3 = nb3;
        gv0 = ng0; gv1 = ng1; gv2 = ng2;
    }
    a0 += __shfl_xor(a0,16,64); a0 += __shfl_xor(a0,32,64);
    a1 += __shfl_xor(a1,16,64); a1 += __shfl_xor(a1,32,64);
    a2 += __shfl_xor(a2,16,64); a2 += __shfl_xor(a2,32,64);
    if (ln < 16 && n0 < N){
        size_t o = (size_t)n*TV + c*3;
        out[o+0] = vprev[o+0] + a0;
        out[o+1] = vprev[o+1] + a1;
        out[o+2] = vprev[o+2] + a2;
    }
}

// ============================================================================
extern "C" void kernel_launch(void* const* d_in, const int* in_sizes, int n_in,
                              void* d_out, int out_size, void* d_ws, size_t ws_size,
                              hipStream_t stream){
    const float* h      = (const float*)d_in[1];
    const void*  eidx   = d_in[2];
    const float* frames = (const float*)d_in[3];
    const float* vprev  = (const float*)d_in[5];
    const float* W1  = (const float*)d_in[6];
    const float* b1  = (const float*)d_in[7];
    const float* g1  = (const float*)d_in[8];
    const float* bb1 = (const float*)d_in[9];
    const float* W2  = (const float*)d_in[10];
    const float* b2  = (const float*)d_in[11];
    const float* g2  = (const float*)d_in[12];
    const float* bb2 = (const float*)d_in[13];
    const float* Wi  = (const float*)d_in[14];
    const float* bi  = (const float*)d_in[15];
    const float* gi  = (const float*)d_in[16];
    const float* bbi = (const float*)d_in[17];
    float* out = (float*)d_out;

    const int N = in_sizes[1] / DD;
    const int E = in_sizes[2] / 2;
    const int Np = ((N + 63) / 64) * 64;

    // workspace carve-up
    float* bias_t = (float*)d_ws;                     // 1024
    float* gi_t   = bias_t + 1024;                    // 512
    float* bbi_t  = gi_t + 512;                       // 512
    float* vecs   = bbi_t + 512;                      // N*48
    float* gvec   = vecs + (size_t)N*TV;              // N*48
    unsigned short* Wtb = (unsigned short*)(gvec + (size_t)N*TV);  // 1024*128
    unsigned short* hbh = Wtb + 1024*128;             // Np*128
    unsigned short* hbl = hbh + (size_t)Np*128;       // Np*128
    unsigned short* P   = hbl + (size_t)Np*128;       // Np*1024 bf16
    int* idx32  = (int*)(P + (size_t)Np*1024);        // 2E
    int* cnt    = idx32 + 2*(size_t)E;                // N
    int* startp = cnt + N;                            // N+1
    int* cursor = startp + N + 1;                     // N
    int* elist  = cursor + N;                         // E
    int* dflag  = elist + E;                          // 1

    int nchk = E < 4096 ? E : 4096;
    prep_k<<<(N + 255)/256, 256, 0, stream>>>((const int*)eidx, nchk, dflag, cnt, N);
    cvt_hist<<<(2*E + 255)/256, 256, 0, stream>>>(eidx, idx32, cnt, 2*E, E, dflag);
    build_wt<<<1024, 128, 0, stream>>>(Wi, bi, gi, bbi, Wtb, bias_t, gi_t, bbi_t);
    vinit<<<(N + 3)/4, 256, 0, stream>>>(h, W1, b1, g1, bb1, W2, b2, g2, bb2,
                                         frames, vecs, gvec, hbh, hbl, N);
    gemm_mfma<<<dim3(4, Np/64), 256, 0, stream>>>(hbh, hbl, Wtb, bias_t, P, Np);
    scan_k<<<1, 1024, 0, stream>>>(cnt, startp, cursor, N);
    scatter_k<<<(E + 255)/256, 256, 0, stream>>>(idx32, cursor, elist, E);
    node_k<<<(N + 3)/4, 256, 0, stream>>>(P, vecs, gvec, frames, startp, elist,
                                          vprev, gi_t, bbi_t, out, N);
    (void)ws_size; (void)n_in; (void)out_size;
}

// Round 12
// 564.008 us; speedup vs baseline: 1.2982x; 1.0320x over previous
//
#include <hip/hip_runtime.h>

// ============================================================================
// VectorChannel, round 11 re-land (broker timeout): parallel 3-phase scan.
//   Tail = 376us of 582; arithmetic bounds all tail kernels to ~105us except
//   scan_k (1 workgroup, 25 serial iters, 4 barriers each) -> prime suspect.
//   node_k / gemm / vinit / CSR kernels byte-identical to round 10.
// ============================================================================

#define DD 128
#define VV 16
#define TV 48      // 3*V
#define NK 512     // 2*V*V
#define LOG2E 1.44269504088896340736f

typedef __attribute__((ext_vector_type(8))) short short8;   // 8 bf16 (4 VGPR)
typedef __attribute__((ext_vector_type(4))) float f32x4;

#if __has_builtin(__builtin_amdgcn_exp2f)
#define EXP2F(x) __builtin_amdgcn_exp2f(x)
#else
#define EXP2F(x) exp2f(x)
#endif
#if __has_builtin(__builtin_amdgcn_rcpf)
#define RCPF(x) __builtin_amdgcn_rcpf(x)
#else
#define RCPF(x) (1.0f/(x))
#endif

__device__ __forceinline__ unsigned short f2bf(float f){
    union{float f; unsigned u;} v; v.f = f;
    unsigned r = v.u + 0x7fffu + ((v.u >> 16) & 1u);   // RTNE
    return (unsigned short)(r >> 16);
}
__device__ __forceinline__ float bf2f(unsigned short h){
    union{unsigned u; float f;} v; v.u = ((unsigned)h) << 16; return v.f;
}
__device__ __forceinline__ float bf2f_hi(unsigned u){
    union{unsigned u; float f;} v; v.u = u & 0xffff0000u; return v.f;
}
__device__ __forceinline__ float bf2f_lo(unsigned u){
    union{unsigned u; float f;} v; v.u = u << 16; return v.f;
}
__device__ __forceinline__ void unpack8(uint4 q, float* d){
    d[0]=bf2f_lo(q.x); d[1]=bf2f_hi(q.x);
    d[2]=bf2f_lo(q.y); d[3]=bf2f_hi(q.y);
    d[4]=bf2f_lo(q.z); d[5]=bf2f_hi(q.z);
    d[6]=bf2f_lo(q.w); d[7]=bf2f_hi(q.w);
}
__device__ __forceinline__ float waveRedSum64(float v){
    #pragma unroll
    for (int off = 32; off > 0; off >>= 1) v += __shfl_xor(v, off, 64);
    return v;
}

// --- zero cnt + detect int64 (block 0) ---------------------------------------
__global__ void prep_k(const int* __restrict__ p, int nchk, int* __restrict__ flag,
                       int* __restrict__ cnt, int N){
    int i = blockIdx.x*blockDim.x + threadIdx.x;
    if (i < N) cnt[i] = 0;
    if (blockIdx.x == 0){
        __shared__ int s;
        if (threadIdx.x == 0) s = 0;
        __syncthreads();
        int nz = 0;
        for (int k = threadIdx.x; k < nchk; k += blockDim.x) nz |= (p[2*k+1] != 0);
        if (nz) atomicOr(&s, 1);
        __syncthreads();
        if (threadIdx.x == 0) *flag = s ? 0 : 1;   // 1 => int64
    }
}

// convert indices to i32 AND histogram the cols
__global__ void cvt_hist(const void* __restrict__ src, int* __restrict__ dst,
                         int* __restrict__ cnt, int n, int E,
                         const int* __restrict__ flag){
    int i = blockIdx.x*blockDim.x + threadIdx.x;
    if (i >= n) return;
    int v = (*flag) ? (int)((const long long*)src)[i] : ((const int*)src)[i];
    dst[i] = v;
    if (i >= E) atomicAdd(&cnt[v], 1);   // i>=E => col array
}

// --- 3-phase parallel exclusive scan -----------------------------------------
// Phase A: per-block (256) local exclusive prefix into start[], block sums.
__global__ __launch_bounds__(256) void scan_blk(const int* __restrict__ cnt,
        int* __restrict__ start, int* __restrict__ bsum, int N){
    __shared__ int wsum[4];
    int tid = threadIdx.x, lane = tid & 63, wid = tid >> 6;
    int i = blockIdx.x*256 + tid;
    int x = (i < N) ? cnt[i] : 0;
    int v = x;
    #pragma unroll
    for (int off = 1; off < 64; off <<= 1){
        int t = __shfl_up(v, off, 64);
        if (lane >= off) v += t;
    }
    if (lane == 63) wsum[wid] = v;
    __syncthreads();
    int woff = 0;
    #pragma unroll
    for (int k = 0; k < 4; k++) woff += (k < wid) ? wsum[k] : 0;
    if (i < N) start[i] = v - x + woff;           // local exclusive
    if (tid == 255) bsum[blockIdx.x] = woff + v;  // block total
}

// Phase B: one block scans the NB block sums (NB <= 1024), writes start[N].
__global__ __launch_bounds__(1024) void scan_top(const int* __restrict__ bsum,
        int* __restrict__ boff, int* __restrict__ start, int NB, int N){
    __shared__ int wsum[16];
    __shared__ int woff[16];
    int tid = threadIdx.x, lane = tid & 63, wid = tid >> 6;
    int x = (tid < NB) ? bsum[tid] : 0;
    int v = x;
    #pragma unroll
    for (int off = 1; off < 64; off <<= 1){
        int t = __shfl_up(v, off, 64);
        if (lane >= off) v += t;
    }
    if (lane == 63) wsum[wid] = v;
    __syncthreads();
    if (wid == 0 && lane < 16){
        int s = wsum[lane];
        int sv = s;
        #pragma unroll
        for (int off = 1; off < 16; off <<= 1){
            int t = __shfl_up(sv, off, 64);
            if (lane >= off) sv += t;
        }
        woff[lane] = sv - s;
    }
    __syncthreads();
    if (tid < NB) boff[tid] = v - x + woff[wid];  // exclusive block offset
    if (tid == 1023) start[N] = woff[15] + v;     // grand total (pad x=0)
}

// Phase C: add block offsets; fill cursor.
__global__ void scan_add(int* __restrict__ start, int* __restrict__ cursor,
                         const int* __restrict__ boff, int N){
    int i = blockIdx.x*blockDim.x + threadIdx.x;
    if (i < N){
        int s = start[i] + boff[i >> 8];
        start[i] = s;
        cursor[i] = s;
    }
}

__global__ void scatter_k(const int* __restrict__ idx, int* __restrict__ cursor,
                          int* __restrict__ elist, int E){
    int e = blockIdx.x*blockDim.x + threadIdx.x;
    if (e >= E) return;
    int col = idx[E + e], row = idx[e];
    int pos = atomicAdd(&cursor[col], 1);
    elist[pos] = row;
}

// --- build permuted bf16 weight matrix [1024 cols][128 k] + params -----------
// col j<512: PA (c=j/32,kk=j%32 -> k=kk*16+c, Wi[k][0:128], bias bi[k])
//     j>=512: PB (Wi[k][128:256], bias 0).
// gi_t/bbi_t pre-scaled by -log2e for the exp2-form sigmoid.
__global__ void build_wt(const float* __restrict__ Wi, const float* __restrict__ bi,
                         const float* __restrict__ gi, const float* __restrict__ bbi,
                         unsigned short* __restrict__ Wtb, float* __restrict__ bias_t,
                         float* __restrict__ gi_t, float* __restrict__ bbi_t){
    int j = blockIdx.x;        // 0..1023
    int d = threadIdx.x;       // 0..127
    int half = j >> 9;
    int jj = j & 511;
    int c = jj >> 5, kk = jj & 31;
    int k = kk*16 + c;
    Wtb[(size_t)j*128 + d] = f2bf(Wi[k*256 + half*128 + d]);
    if (d == 0){
        bias_t[j] = half ? 0.0f : bi[k];
        if (!half){ gi_t[jj] = -gi[k]*LOG2E; bbi_t[jj] = -bbi[k]*LOG2E; }
    }
}

// --- vector_init (+ h split to bf16 hi/lo, folded) ---------------------------
__global__ __launch_bounds__(256) void vinit(
        const float* __restrict__ h,
        const float* __restrict__ W1, const float* __restrict__ b1,
        const float* __restrict__ g1, const float* __restrict__ bb1,
        const float* __restrict__ W2, const float* __restrict__ b2,
        const float* __restrict__ g2, const float* __restrict__ bb2,
        const float* __restrict__ frames,
        float* __restrict__ vecs, float* __restrict__ gvec,
        unsigned short* __restrict__ hbh, unsigned short* __restrict__ hbl, int N){
    __shared__ float hs[4][DD];
    __shared__ float ts[4][TV];
    int w = threadIdx.x >> 6, l = threadIdx.x & 63;
    int n = blockIdx.x*4 + w;
    int nr = n < N ? n : N-1;
    float hv0 = h[(size_t)nr*DD + l];
    float hv1 = h[(size_t)nr*DD + 64 + l];
    hs[w][l]      = hv0;
    hs[w][l + 64] = hv1;
    if (n < N){     // folded cast_h: split to bf16 hi/lo
        unsigned short h0 = f2bf(hv0), h1 = f2bf(hv1);
        hbh[(size_t)n*DD + l]      = h0;
        hbh[(size_t)n*DD + 64 + l] = h1;
        hbl[(size_t)n*DD + l]      = f2bf(hv0 - bf2f(h0));
        hbl[(size_t)n*DD + 64 + l] = f2bf(hv1 - bf2f(h1));
    }
    __syncthreads();

    float o1 = 0.0f;
    if (l < TV){
        o1 = b1[l];
        const float* wr = W1 + l*DD;
        #pragma unroll
        for (int d = 0; d < DD; d += 4){
            float4 w4 = *(const float4*)(wr + d);
            o1 += hs[w][d]*w4.x + hs[w][d+1]*w4.y + hs[w][d+2]*w4.z + hs[w][d+3]*w4.w;
        }
    }
    float s  = waveRedSum64(l < TV ? o1 : 0.0f);
    float mu = s * (1.0f/TV);
    float dv = l < TV ? (o1 - mu) : 0.0f;
    float sq = waveRedSum64(dv*dv);
    float inv = rsqrtf(sq*(1.0f/TV) + 1e-5f);
    if (l < TV){
        float y = g1[l]*(dv*inv) + bb1[l];
        ts[w][l] = y / (1.0f + __expf(-y));
    }
    __syncthreads();

    float o2 = 0.0f;
    if (l < TV){
        o2 = b2[l];
        const float* wr = W2 + l*TV;
        #pragma unroll
        for (int j = 0; j < TV; j += 4){
            float4 w4 = *(const float4*)(wr + j);
            o2 += ts[w][j]*w4.x + ts[w][j+1]*w4.y + ts[w][j+2]*w4.z + ts[w][j+3]*w4.w;
        }
    }
    s  = waveRedSum64(l < TV ? o2 : 0.0f);
    mu = s * (1.0f/TV);
    dv = l < TV ? (o2 - mu) : 0.0f;
    sq = waveRedSum64(dv*dv);
    inv = rsqrtf(sq*(1.0f/TV) + 1e-5f);
    __syncthreads();
    if (l < TV){
        float y = g2[l]*(dv*inv) + bb2[l];
        float t2 = y / (1.0f + __expf(-y));
        if (n < N) vecs[(size_t)n*TV + l] = t2;
        ts[w][l] = t2;
    }
    __syncthreads();
    if (l < TV && n < N){
        int cc = l/3, oo = l%3;  // g[n][cc][oo] = sum_j R[oo][j]*v[cc][j]
        const float* R = frames + (size_t)n*9;
        float gv = R[oo*3+0]*ts[w][cc*3+0] + R[oo*3+1]*ts[w][cc*3+1] + R[oo*3+2]*ts[w][cc*3+2];
        gvec[(size_t)n*TV + l] = gv;
    }
}

// --- P = (h_hi + h_lo) @ Wtb^T + bias : bf16 MFMA, bf16 out ------------------
__global__ __launch_bounds__(256) void gemm_mfma(
        const unsigned short* __restrict__ hbh, const unsigned short* __restrict__ hbl,
        const unsigned short* __restrict__ Wtb, const float* __restrict__ bias_t,
        unsigned short* __restrict__ P, int Np){
    int wv = threadIdx.x >> 6, l = threadIdx.x & 63;
    int lr = l & 15, g = l >> 4;
    int m0 = (blockIdx.y*4 + wv)*16;
    int n0 = blockIdx.x*256;

    f32x4 acc[16];
    #pragma unroll
    for (int nf = 0; nf < 16; nf++) acc[nf] = (f32x4){0.f,0.f,0.f,0.f};

    const unsigned short* arow_h = hbh + (size_t)(m0 + lr)*128;
    const unsigned short* arow_l = hbl + (size_t)(m0 + lr)*128;

    #pragma unroll
    for (int ks = 0; ks < 128; ks += 32){
        int kb = ks + 4*g;
        short8 ah, al;
        ((ushort4*)&ah)[0] = *(const ushort4*)(arow_h + kb);
        ((ushort4*)&ah)[1] = *(const ushort4*)(arow_h + kb + 16);
        ((ushort4*)&al)[0] = *(const ushort4*)(arow_l + kb);
        ((ushort4*)&al)[1] = *(const ushort4*)(arow_l + kb + 16);
        #pragma unroll
        for (int nf = 0; nf < 16; nf++){
            const unsigned short* brow = Wtb + (size_t)(n0 + nf*16 + lr)*128;
            short8 b;
            ((ushort4*)&b)[0] = *(const ushort4*)(brow + kb);
            ((ushort4*)&b)[1] = *(const ushort4*)(brow + kb + 16);
            acc[nf] = __builtin_amdgcn_mfma_f32_16x16x32_bf16(ah, b, acc[nf], 0, 0, 0);
            acc[nf] = __builtin_amdgcn_mfma_f32_16x16x32_bf16(al, b, acc[nf], 0, 0, 0);
        }
    }
    #pragma unroll
    for (int nf = 0; nf < 16; nf++){
        int col = n0 + nf*16 + lr;
        float bs = bias_t[col];
        #pragma unroll
        for (int r = 0; r < 4; r++){
            P[(size_t)(m0 + g*4 + r)*1024 + col] = f2bf(acc[nf][r] + bs);
        }
    }
}

// --- node kernel: one wave/node, 4 edges in flight, 1-deep load pipeline -----
__global__ __launch_bounds__(256) void node_k(
        const unsigned short* __restrict__ P, const float* __restrict__ vecs,
        const float* __restrict__ gvec, const float* __restrict__ frames,
        const int* __restrict__ start, const int* __restrict__ elist,
        const float* __restrict__ vprev, const float* __restrict__ gi_t,
        const float* __restrict__ bbi_t, float* __restrict__ out, int N){
    __shared__ float svs[4][4][100];   // [wave][sub][48 vi + 48 vj + pad]
    int wv = threadIdx.x >> 6, ln = threadIdx.x & 63;
    int sub = ln >> 4, c = ln & 15;
    int n0 = blockIdx.x*4 + wv;
    int n = n0 < N ? n0 : N-1;

    {   // vi into every sub slot
        const float* vc = vecs + (size_t)n*TV + c*3;
        svs[wv][sub][c*3+0] = vc[0];
        svs[wv][sub][c*3+1] = vc[1];
        svs[wv][sub][c*3+2] = vc[2];
    }
    float R[9];
    #pragma unroll
    for (int i = 0; i < 9; i++) R[i] = frames[(size_t)n*9 + i];

    float pa[32];          // PA unpacked once per node
    {
        const uint4* p4 = (const uint4*)(P + (size_t)n*1024 + c*32);
        #pragma unroll
        for (int q = 0; q < 4; q++) unpack8(p4[q], pa + 8*q);
    }
    int e0 = start[n], e1 = start[n+1];
    float a0 = 0.f, a1 = 0.f, a2 = 0.f;

    // ---- pipeline prologue: load edge t's PB + gvec (clamped-safe) ----
    int t = e0 + sub;
    int rcur = elist[t < e1 ? t : 0];
    uint4 pb0, pb1, pb2, pb3;
    float gv0, gv1, gv2;
    {
        const uint4* p4 = (const uint4*)(P + (size_t)rcur*1024 + 512 + c*32);
        pb0 = p4[0]; pb1 = p4[1]; pb2 = p4[2]; pb3 = p4[3];
        const float* gr = gvec + (size_t)rcur*TV + c*3;
        gv0 = gr[0]; gv1 = gr[1]; gv2 = gr[2];
    }

    for (; t < e1; t += 4){
        // ---- issue NEXT edge's loads before computing current ----
        int tn = t + 4;
        int rnext = elist[tn < e1 ? tn : 0];
        uint4 nb0, nb1, nb2, nb3;
        float ng0, ng1, ng2;
        {
            const uint4* p4 = (const uint4*)(P + (size_t)rnext*1024 + 512 + c*32);
            nb0 = p4[0]; nb1 = p4[1]; nb2 = p4[2]; nb3 = p4[3];
            const float* gr = gvec + (size_t)rnext*TV + c*3;
            ng0 = gr[0]; ng1 = gr[1]; ng2 = gr[2];
        }

        // ---- compute current edge from registers ----
        float l[32];
        unpack8(pb0, l+0); unpack8(pb1, l+8); unpack8(pb2, l+16); unpack8(pb3, l+24);
        float sA = 0.f, sB = 0.f, qA = 0.f, qB = 0.f;
        #pragma unroll
        for (int i = 0; i < 16; i++){
            float xa = pa[i]    + l[i];    l[i]    = xa; sA += xa; qA = fmaf(xa, xa, qA);
            float xb = pa[16+i] + l[16+i]; l[16+i] = xb; sB += xb; qB = fmaf(xb, xb, qB);
        }
        float s = sA + sB, sq = qA + qB;
        #pragma unroll
        for (int off = 1; off < 16; off <<= 1){
            s  += __shfl_xor(s,  off, 64);
            sq += __shfl_xor(sq, off, 64);
        }
        float mu  = s * (1.0f/NK);
        float var = fmaf(-mu, mu, sq * (1.0f/NK));
        float inv = rsqrtf(var + 1e-5f);
        float nmi = -mu * inv;

        // vj_in_i for channel c: Ri^T @ gvec[row][c]
        svs[wv][sub][48+c*3+0] = R[0]*gv0 + R[3]*gv1 + R[6]*gv2;
        svs[wv][sub][48+c*3+1] = R[1]*gv0 + R[4]*gv1 + R[7]*gv2;
        svs[wv][sub][48+c*3+2] = R[2]*gv0 + R[5]*gv1 + R[8]*gv2;

        // weights in place: w = rcp(1 + exp2(fma(g2, z, b2))), z = fma(l,inv,nmi)
        {
            const float4* g4 = (const float4*)(gi_t  + c*32);
            const float4* b4 = (const float4*)(bbi_t + c*32);
            #pragma unroll
            for (int q = 0; q < 8; q++){
                float4 gg = g4[q], bb = b4[q];
                float gx[4] = {gg.x, gg.y, gg.z, gg.w};
                float bx[4] = {bb.x, bb.y, bb.z, bb.w};
                #pragma unroll
                for (int r = 0; r < 4; r++){
                    float z   = fmaf(l[4*q+r], inv, nmi);
                    float arg = fmaf(gx[r], z, bx[r]);
                    l[4*q+r]  = RCPF(1.0f + EXP2F(arg));
                }
            }
        }
        // bilinear: acc[o] += sv[ch][o] * w[ch], 24 float4 LDS reads
        {
            const float4* sv4 = (const float4*)&svs[wv][sub][0];
            #pragma unroll
            for (int q = 0; q < 24; q++){
                float4 x = sv4[q];
                {   const int e = 4*q+0, ch = e/3, o = e%3;
                    float p = x.x * l[ch];
                    if (o==0) a0 += p; else if (o==1) a1 += p; else a2 += p; }
                {   const int e = 4*q+1, ch = e/3, o = e%3;
                    float p = x.y * l[ch];
                    if (o==0) a0 += p; else if (o==1) a1 += p; else a2 += p; }
                {   const int e = 4*q+2, ch = e/3, o = e%3;
                    float p = x.z * l[ch];
                    if (o==0) a0 += p; else if (o==1) a1 += p; else a2 += p; }
                {   const int e = 4*q+3, ch = e/3, o = e%3;
                    float p = x.w * l[ch];
                    if (o==0) a0 += p; else if (o==1) a1 += p; else a2 += p; }
            }
        }
        // ---- rotate pipeline registers ----
        pb0 = nb0; pb1 = nb1; pb2 = nb2; pb3 = nb3;
        gv0 = ng0; gv1 = ng1; gv2 = ng2;
    }
    a0 += __shfl_xor(a0,16,64); a0 += __shfl_xor(a0,32,64);
    a1 += __shfl_xor(a1,16,64); a1 += __shfl_xor(a1,32,64);
    a2 += __shfl_xor(a2,16,64); a2 += __shfl_xor(a2,32,64);
    if (ln < 16 && n0 < N){
        size_t o = (size_t)n*TV + c*3;
        out[o+0] = vprev[o+0] + a0;
        out[o+1] = vprev[o+1] + a1;
        out[o+2] = vprev[o+2] + a2;
    }
}

// ============================================================================
extern "C" void kernel_launch(void* const* d_in, const int* in_sizes, int n_in,
                              void* d_out, int out_size, void* d_ws, size_t ws_size,
                              hipStream_t stream){
    const float* h      = (const float*)d_in[1];
    const void*  eidx   = d_in[2];
    const float* frames = (const float*)d_in[3];
    const float* vprev  = (const float*)d_in[5];
    const float* W1  = (const float*)d_in[6];
    const float* b1  = (const float*)d_in[7];
    const float* g1  = (const float*)d_in[8];
    const float* bb1 = (const float*)d_in[9];
    const float* W2  = (const float*)d_in[10];
    const float* b2  = (const float*)d_in[11];
    const float* g2  = (const float*)d_in[12];
    const float* bb2 = (const float*)d_in[13];
    const float* Wi  = (const float*)d_in[14];
    const float* bi  = (const float*)d_in[15];
    const float* gi  = (const float*)d_in[16];
    const float* bbi = (const float*)d_in[17];
    float* out = (float*)d_out;

    const int N = in_sizes[1] / DD;
    const int E = in_sizes[2] / 2;
    const int Np = ((N + 63) / 64) * 64;
    const int NB = (N + 255) / 256;               // scan blocks (<=1024)

    // workspace carve-up
    float* bias_t = (float*)d_ws;                     // 1024
    float* gi_t   = bias_t + 1024;                    // 512
    float* bbi_t  = gi_t + 512;                       // 512
    float* vecs   = bbi_t + 512;                      // N*48
    float* gvec   = vecs + (size_t)N*TV;              // N*48
    unsigned short* Wtb = (unsigned short*)(gvec + (size_t)N*TV);  // 1024*128
    unsigned short* hbh = Wtb + 1024*128;             // Np*128
    unsigned short* hbl = hbh + (size_t)Np*128;       // Np*128
    unsigned short* P   = hbl + (size_t)Np*128;       // Np*1024 bf16
    int* idx32  = (int*)(P + (size_t)Np*1024);        // 2E
    int* cnt    = idx32 + 2*(size_t)E;                // N
    int* startp = cnt + N;                            // N+1
    int* cursor = startp + N + 1;                     // N
    int* elist  = cursor + N;                         // E
    int* dflag  = elist + E;                          // 1
    int* bsum   = dflag + 1;                          // NB
    int* boff   = bsum + 1024;                        // NB

    int nchk = E < 4096 ? E : 4096;
    prep_k<<<(N + 255)/256, 256, 0, stream>>>((const int*)eidx, nchk, dflag, cnt, N);
    cvt_hist<<<(2*E + 255)/256, 256, 0, stream>>>(eidx, idx32, cnt, 2*E, E, dflag);
    build_wt<<<1024, 128, 0, stream>>>(Wi, bi, gi, bbi, Wtb, bias_t, gi_t, bbi_t);
    vinit<<<(N + 3)/4, 256, 0, stream>>>(h, W1, b1, g1, bb1, W2, b2, g2, bb2,
                                         frames, vecs, gvec, hbh, hbl, N);
    gemm_mfma<<<dim3(4, Np/64), 256, 0, stream>>>(hbh, hbl, Wtb, bias_t, P, Np);
    scan_blk<<<NB, 256, 0, stream>>>(cnt, startp, bsum, N);
    scan_top<<<1, 1024, 0, stream>>>(bsum, boff, startp, NB, N);
    scan_add<<<NB, 256, 0, stream>>>(startp, cursor, boff, N);
    scatter_k<<<(E + 255)/256, 256, 0, stream>>>(idx32, cursor, elist, E);
    node_k<<<(N + 3)/4, 256, 0, stream>>>(P, vecs, gvec, frames, startp, elist,
                                          vprev, gi_t, bbi_t, out, N);
    (void)ws_size; (void)n_in; (void)out_size;
}